// Round 1
// baseline (212.540 us; speedup 1.0000x reference)
//
#include <hip/hip_runtime.h>
#include <hip/hip_bf16.h>
#include <math.h>

#define B_ 4
#define N_ 2048
#define D_ 512
#define H_ 8
// NORM * log2(e): scores pre-scaled so softmax uses exp2 directly.
#define NORM2_ 0.18033688011112042f

typedef __attribute__((ext_vector_type(8))) short short8;   // 8 bf16 (4 VGPRs)
typedef __attribute__((ext_vector_type(4))) float f32x4;    // MFMA C/D
#define MFMA16(a, b, c) __builtin_amdgcn_mfma_f32_16x16x32_bf16(a, b, c, 0, 0, 0)
#define EXP2(x) __builtin_amdgcn_exp2f(x)

// pack two f32 -> two bf16 (RNE, native v_cvt_pk_bf16_f32); .x at low half
static __device__ __forceinline__ uint32_t pk2(float lo, float hi) {
  __hip_bfloat162 h = __float22bfloat162_rn(make_float2(lo, hi));
  return *(reinterpret_cast<uint32_t*>(&h));
}

// async global->LDS, 16B per lane. LDS dest must be wave-uniform base + lane*16.
static __device__ __forceinline__ void async16(const ushort* lds, const ushort* g) {
  __builtin_amdgcn_global_load_lds(
      (const __attribute__((address_space(1))) uint32_t*)g,
      (__attribute__((address_space(3))) uint32_t*)(ushort*)lds, 16, 0, 0);
}

// ---------------- fused prep: mask pack + all fp32->bf16 conversions ----------------
__global__ __launch_bounds__(256) void prep(const float* __restrict__ q,
                                            const int* __restrict__ mask,
                                            const float* __restrict__ wq,
                                            const float* __restrict__ wk,
                                            const float* __restrict__ wc,
                                            ushort* __restrict__ Xb,
                                            ushort* __restrict__ Wb,
                                            uint32_t* __restrict__ pk) {
  const int bx = blockIdx.x;
  if (bx < 2048) {
    const int lane = threadIdx.x & 63;
    const int wid = ((bx << 8) + threadIdx.x) >> 6;  // 8192 waves
    for (int i = wid; i < 65536; i += 8192) {        // 256-key chunks
      const int4 m = ((const int4*)mask)[(size_t)i * 64 + lane];
      uint32_t nib = (uint32_t)(m.x != 0) | ((uint32_t)(m.y != 0) << 1) |
                     ((uint32_t)(m.z != 0) << 2) | ((uint32_t)(m.w != 0) << 3);
      nib |= __shfl_xor(nib, 1) << 4;
      nib |= __shfl_xor(nib, 2) << 8;
      nib |= __shfl_xor(nib, 4) << 16;
      if ((lane & 7) == 0) pk[i * 8 + (lane >> 3)] = nib;
    }
  } else if (bx < 3072) {
    const int i = ((bx - 2048) << 8) + threadIdx.x;
    for (int j = i; j < 1048576; j += 262144) {
      const float4 v = ((const float4*)q)[j];
      uint2 o; o.x = pk2(v.x, v.y); o.y = pk2(v.z, v.w);
      ((uint2*)Xb)[j] = o;
    }
  } else {
    const int i = ((bx - 3072) << 8) + threadIdx.x;
    for (int j = i; j < 196608; j += 24576) {
      const int wi = j >> 16, off = j & 65535;
      const float* src = (wi == 0) ? wq : (wi == 1) ? wk : wc;
      const float4 v = ((const float4*)src)[off];
      uint2 o; o.x = pk2(v.x, v.y); o.y = pk2(v.z, v.w);
      ((uint2*)Wb)[j] = o;
    }
  }
}

// ---------------- 128x128 bf16 MFMA GEMM: C = X @ W^T ----------------
template <int F32OUT>
__global__ __launch_bounds__(256) void gemm128(const ushort* __restrict__ X,
                                               const ushort* __restrict__ W0,
                                               const ushort* __restrict__ W1,
                                               void* __restrict__ C0,
                                               void* __restrict__ C1,
                                               float s0, float s1) {
  const ushort* Wp = (blockIdx.z == 0) ? W0 : W1;
  void* Cp = (blockIdx.z == 0) ? C0 : C1;
  const float sc = (blockIdx.z == 0) ? s0 : s1;
  const int t = threadIdx.x;
  const int w = t >> 6, lane = t & 63, quad = lane >> 4, c = lane & 15;
  const int wm = w & 1, wn = w >> 1;
  const int n0 = blockIdx.x * 128, m0 = blockIdx.y * 128;
  __shared__ __align__(16) ushort Xs[128][64];
  __shared__ __align__(16) ushort Ws[128][64];
  f32x4 acc[4][4];
#pragma unroll
  for (int i = 0; i < 4; ++i)
#pragma unroll
    for (int j = 0; j < 4; ++j) acc[i][j] = (f32x4){0.f, 0.f, 0.f, 0.f};

  for (int k0 = 0; k0 < D_; k0 += 64) {
    __syncthreads();
#pragma unroll
    for (int g = 0; g < 4; ++g) {
      const int id = w * 256 + g * 64 + lane;
      const int row = id >> 3, lch = id & 7;
      const int gch = lch ^ (row & 7);
      async16(&Xs[row][lch * 8], X + (size_t)(m0 + row) * D_ + k0 + gch * 8);
      async16(&Ws[row][lch * 8], Wp + (size_t)(n0 + row) * D_ + k0 + gch * 8);
    }
    __syncthreads();
#pragma unroll
    for (int s = 0; s < 2; ++s) {
      short8 af[4], bt[4];
#pragma unroll
      for (int i = 0; i < 4; ++i) {
        const int rA = wn * 64 + i * 16 + c;
        af[i] = *(const short8*)&Ws[rA][(((s * 4 + quad) ^ (rA & 7)) & 7) * 8];
        const int rB = wm * 64 + i * 16 + c;
        bt[i] = *(const short8*)&Xs[rB][(((s * 4 + quad) ^ (rB & 7)) & 7) * 8];
      }
#pragma unroll
      for (int i = 0; i < 4; ++i)
#pragma unroll
        for (int j = 0; j < 4; ++j) acc[i][j] = MFMA16(af[i], bt[j], acc[i][j]);
    }
  }
#pragma unroll
  for (int i = 0; i < 4; ++i)
#pragma unroll
    for (int j = 0; j < 4; ++j) {
      const size_t off =
          (size_t)(m0 + wm * 64 + j * 16 + c) * D_ + n0 + wn * 64 + i * 16 + quad * 4;
      if (F32OUT) {
        float4 v; v.x = acc[i][j][0]; v.y = acc[i][j][1]; v.z = acc[i][j][2]; v.w = acc[i][j][3];
        *(float4*)((float*)Cp + off) = v;
      } else {
        uint2 uv;
        uv.x = pk2(acc[i][j][0] * sc, acc[i][j][1] * sc);
        uv.y = pk2(acc[i][j][2] * sc, acc[i][j][3] * sc);
        *(uint2*)((ushort*)Cp + off) = uv;
      }
    }
}

// ---------------- flash attention: bf16 MFMA, V == K, no online max ----------------
// Single-buffer LDS (25.6 KB, 4 blocks/CU — r8's best config) + ones-MFMA l.
// Scores in log2 domain (Q pre-scaled by NORM*log2e):
//   p = masked ? 0 : exp2(s); O += p*V; l via ones-row MFMA; epilogue O/l.
__global__ __launch_bounds__(256) void attn_mfma(const ushort* __restrict__ Qb,
                                                 const ushort* __restrict__ Kb,
                                                 const uint32_t* __restrict__ pk,
                                                 ushort* __restrict__ Ab) {
  const int qt = blockIdx.x, h = blockIdx.y, b = blockIdx.z;
  const int q0 = qt * 64;
  const int t = threadIdx.x;
  const int w = t >> 6, lane = t & 63, quad = lane >> 4, c = lane & 15;

  __shared__ __align__(16) ushort Ks[64][64];        // 8K: K rows, swizzled chunks
  __shared__ __align__(16) uint32_t KtU[64][32];     // 8K: V^T key-pair u32, swizzled
  __shared__ __align__(16) ushort QP[4][16][72];     // 9.2K: Qs (staging) then Pq
  ushort(*Qs)[64] = (ushort(*)[64]) & QP[0][0][0];
  ushort(*Pq)[16][72] = QP;

  // ---- stage Q once (async DMA) ----
#pragma unroll
  for (int p = 0; p < 2; ++p) {
    const int id = t + p * 256;
    const int row = id >> 3, lch = id & 7, gch = lch ^ (row & 7);
    async16(&Qs[row][lch * 8], Qb + (size_t)(b * N_ + q0 + row) * D_ + h * 64 + gch * 8);
  }
  __syncthreads();
  const int rq = (w << 4) + c;
  const short8 bq0 = *(const short8*)&Qs[rq][((quad ^ (rq & 7)) & 7) * 8];
  const short8 bq1 = *(const short8*)&Qs[rq][(((4 + quad) ^ (rq & 7)) & 7) * 8];

  short8 vones;
#pragma unroll
  for (int i = 0; i < 8; ++i) vones[i] = (short)0x3F80;  // bf16 1.0 splat

  f32x4 o[4];
#pragma unroll
  for (int i = 0; i < 4; ++i) o[i] = (f32x4){0.f, 0.f, 0.f, 0.f};
  f32x4 o5 = (f32x4){0.f, 0.f, 0.f, 0.f};  // l accumulator (ones-MFMA, rows identical)

  const int kp = t >> 3, ch = t & 7;  // staging role: key-pair, d-chunk
  const int r0 = 2 * kp, r1 = r0 + 1;
  const int ksw0 = ((ch ^ (r0 & 7)) & 7) * 8, ksw1 = ((ch ^ (r1 & 7)) & 7) * 8;
  const ushort* kb0 = Kb + (size_t)(b * N_ + 2 * kp) * D_ + h * 64 + ch * 8;
  const uint32_t* pkq = pk + ((size_t)(b * N_ + q0 + (w << 4) + c) << 6);

  // prefetched tile data (registers)
  uint4 c0 = *(const uint4*)kb0;
  uint4 c1 = *(const uint4*)(kb0 + D_);
  uint2 cm = *(const uint2*)pkq;
  uint4 nx0, nx1; uint2 nxm;

  const int NT = N_ / 64;
  for (int kt = 0; kt < NT; ++kt) {
    __syncthreads();  // prior tile's frag reads (and initial Qs reads) done
    // ---- stage K tile from registers (rows + u32 key-pair transpose) ----
    *(uint4*)&Ks[r0][ksw0] = c0;
    *(uint4*)&Ks[r1][ksw1] = c1;
    const uint32_t* a0 = (const uint32_t*)&c0;
    const uint32_t* a1 = (const uint32_t*)&c1;
#pragma unroll
    for (int m = 0; m < 4; ++m) {
      const uint32_t lo = __builtin_amdgcn_perm(a1[m], a0[m], 0x05040100);  // even d
      const uint32_t hi = __builtin_amdgcn_perm(a1[m], a0[m], 0x07060302);  // odd d
      const int j0 = 2 * m, j1 = 2 * m + 1;
      KtU[ch * 8 + j0][(kp & 3) | ((((kp >> 2) ^ j0 ^ ch) & 7) << 2)] = lo;
      KtU[ch * 8 + j1][(kp & 3) | ((((kp >> 2) ^ j1 ^ ch) & 7) << 2)] = hi;
    }
    __syncthreads();

    if (kt + 1 < NT) {  // prefetch next tile while computing
      const ushort* kbn = kb0 + (size_t)(kt + 1) * 64 * D_;
      nx0 = *(const uint4*)kbn;
      nx1 = *(const uint4*)(kbn + D_);
      nxm = *(const uint2*)(pkq + (kt + 1) * 2);
    }

    // ---- S^T = K·Q^T; p = masked ? 0 : exp2(s) (exp issues independent of mask chain) ----
#pragma unroll
    for (int tI = 0; tI < 4; ++tI) {
      const int rk = tI * 16 + c;
      const short8 aK0 = *(const short8*)&Ks[rk][((quad ^ (rk & 7)) & 7) * 8];
      const short8 aK1 = *(const short8*)&Ks[rk][(((4 + quad) ^ (rk & 7)) & 7) * 8];
      f32x4 z = (f32x4){0.f, 0.f, 0.f, 0.f};
      z = MFMA16(aK0, bq0, z);
      z = MFMA16(aK1, bq1, z);
      const uint32_t mw = (tI < 2) ? cm.x : cm.y;
      const int bb = ((tI & 1) << 4) + quad * 4;
      uint32_t pb[4];
#pragma unroll
      for (int r = 0; r < 4; ++r) {
        const float e = EXP2(z[r]);                       // unconditional
        pb[r] = ((mw >> (bb + r)) & 1u) ? 0u : __float_as_uint(e);
      }
      const uint32_t pw0 = __builtin_amdgcn_perm(pb[1], pb[0], 0x07060302);
      const uint32_t pw1 = __builtin_amdgcn_perm(pb[3], pb[2], 0x07060302);
      *(uint2*)&Pq[w][c][tI * 16 + quad * 4] = make_uint2(pw0, pw1);
    }

    // ---- O^T += V^T·P^T ; l via ones-MFMA ----
    const short8 bp0 = *(const short8*)&Pq[w][c][quad * 8];
    const short8 bp1 = *(const short8*)&Pq[w][c][32 + quad * 8];
    o5 = MFMA16(vones, bp0, o5);
    o5 = MFMA16(vones, bp1, o5);
#pragma unroll
    for (int dt = 0; dt < 4; ++dt) {
      const int dd = dt * 16 + c;
      const int g = (c & 7) ^ ((2 * dt + (c >> 3)) & 7);
      const short8 aV0 = *(const short8*)&KtU[dd][((quad ^ g) & 7) << 2];
      const short8 aV1 = *(const short8*)&KtU[dd][(((4 + quad) ^ g) & 7) << 2];
      o[dt] = MFMA16(aV0, bp0, o[dt]);
      o[dt] = MFMA16(aV1, bp1, o[dt]);
    }

    if (kt + 1 < NT) { c0 = nx0; c1 = nx1; cm = nxm; }
  }

  // ---- epilogue: O^T[d][q] / l (l = o5[0], all rows equal; no shuffles) ----
  const float inv = 1.f / o5[0];
#pragma unroll
  for (int dt = 0; dt < 4; ++dt) {
    uint2 uv;
    uv.x = pk2(o[dt][0] * inv, o[dt][1] * inv);
    uv.y = pk2(o[dt][2] * inv, o[dt][3] * inv);
    *(uint2*)(Ab + (size_t)(b * N_ + q0 + (w << 4) + c) * D_ + h * 64 + dt * 16 + quad * 4) = uv;
  }
}

extern "C" void kernel_launch(void* const* d_in, const int* in_sizes, int n_in,
                              void* d_out, int out_size, void* d_ws, size_t ws_size,
                              hipStream_t stream) {
  const float* queries = (const float*)d_in[0];
  const int* mask = (const int*)d_in[1];
  const float* Wq = (const float*)d_in[2];
  const float* Wk = (const float*)d_in[3];
  const float* Wc = (const float*)d_in[4];
  float* out = (float*)d_out;

  const size_t nTok = (size_t)B_ * N_;
  const size_t nXD = nTok * D_;
  const size_t nW = (size_t)D_ * D_;
  ushort* Xb = (ushort*)d_ws;
  ushort* Wqb = Xb + nXD;     // Wq|Wk|Wc contiguous
  ushort* Wkb = Wqb + nW;
  ushort* Wcb = Wkb + nW;
  ushort* Qb = Wcb + nW;
  ushort* Kb = Qb + nXD;
  ushort* Ab = Kb + nXD;
  uint32_t* pk = (uint32_t*)(Ab + nXD);

  prep<<<3168, 256, 0, stream>>>(queries, mask, Wq, Wk, Wc, Xb, Wqb, pk);
  gemm128<0><<<dim3(D_ / 128, (int)(nTok / 128), 2), 256, 0, stream>>>(
      Xb, Wqb, Wkb, Qb, Kb, NORM2_, 1.0f);
  attn_mfma<<<dim3(N_ / 64, H_, B_), 256, 0, stream>>>(Qb, Kb, pk, Ab);
  gemm128<1><<<dim3(D_ / 128, (int)(nTok / 128), 1), 256, 0, stream>>>(
      Ab, Wcb, nullptr, out, nullptr, 1.0f, 1.0f);
}